// Round 5
// baseline (287.782 us; speedup 1.0000x reference)
//
#include <hip/hip_runtime.h>

// QuantLinearFP8: out[m,n] = sum_k x[m,k] * w[n,k] * scale[n, k/128] + bias[n]
// M=64, K=4096, N=11008, G=128.
//
// R5: maximal memory-level parallelism.
//  - xcvt: x f32 -> bf16 ONCE, global A-frag-major [k/8][64][8] (512 KB, ws).
//  - pass1: NO LDS, NO barriers. Each lane issues its ENTIRE w k-chunk slice
//    (16x global_load_dwordx4 = 16 KB/wave in flight) up front, then an
//    unrolled 8-step MFMA loop consumes progressively via in-order vmcnt.
//    Scale folded into the f32->bf16 w conversion (kills pg buffers).
//    x frags read global->reg from the L2-hot bf16 buffer, depth-2 prefetch.
//    KSPLIT=16 -> 2752 blocks; VGPR ~126, LDS 0 -> 4 blocks/CU (16 waves).
//  - reduce: 16 partials + bias -> out (deterministic, overwrites poison).

#define Md 64
#define Kd 4096
#define Nd 11008
#define NGROUPS 32
#define BN 64
#define KSPLIT 16
#define KCHUNK 256                 // Kd / KSPLIT
#define NSTEP 8                    // KCHUNK / 32
#define WS_PART_BYTES ((size_t)KSPLIT * Md * Nd * 4)   // 45,088,768 (4096-mult)

typedef __attribute__((ext_vector_type(8))) __bf16 bf16x8;
typedef __attribute__((ext_vector_type(4))) float f32x4;

// ---- pre-pass: x -> bf16, A-frag-major [kgg][m][8], kgg = k/8 ----
__global__ __launch_bounds__(256)
void xcvt_kernel(const float* __restrict__ x, __bf16* __restrict__ xbf)
{
    const int tid = blockIdx.x * 256 + threadIdx.x;   // 32768 = 64 * 512
    const int m   = tid >> 9;       // 0..63
    const int kgg = tid & 511;      // 0..511
    const float* xp = x + (size_t)m * Kd + kgg * 8;
    float4 a = *(const float4*)xp;
    float4 b = *(const float4*)(xp + 4);
    bf16x8 v = {(__bf16)a.x, (__bf16)a.y, (__bf16)a.z, (__bf16)a.w,
                (__bf16)b.x, (__bf16)b.y, (__bf16)b.z, (__bf16)b.w};
    *(bf16x8*)(xbf + ((size_t)kgg * 64 + m) * 8) = v;
}

__global__ __launch_bounds__(256, 4)
void qlinear_pass1(const __bf16* __restrict__ xbf,
                   const float* __restrict__ w,
                   const float* __restrict__ scale,
                   float* __restrict__ ws)
{
    const int tid  = threadIdx.x;
    const int wv   = tid >> 6;
    const int lane = tid & 63;
    const int quad = lane >> 4;
    const int ln   = lane & 15;

    const int n0 = blockIdx.x * BN;
    const int ky = blockIdx.y;

    const int nrow = n0 + wv * 16 + ln;
    const float* wp = w + (size_t)nrow * Kd + ky * KCHUNK + quad * 8;

    // 2 group scales for this chunk (contiguous 8 B)
    const float2 sc2 = *(const float2*)(scale + (size_t)nrow * NGROUPS + ky * 2);
    const float sc[2] = {sc2.x, sc2.y};

    // x frag base for this chunk: frag(step,t) at ((step*4+quad)*64 + t*16+ln)*8
    const __bf16* xb = xbf + ((size_t)ky * 32 * 64) * 8
                     + ((size_t)quad * 64 + ln) * 8;

    // preload x frags for step 0 (oldest in the vmcnt stream)
    bf16x8 xq[2][4];
    #pragma unroll
    for (int t = 0; t < 4; ++t)
        xq[0][t] = *(const bf16x8*)(xb + (size_t)t * 16 * 8);

    // issue the ENTIRE w k-chunk slice: 16 independent dwordx4, fire-and-forget
    float4 wreg[16];
    #pragma unroll
    for (int s = 0; s < NSTEP; ++s) {
        wreg[2 * s]     = *(const float4*)(wp + s * 32);
        wreg[2 * s + 1] = *(const float4*)(wp + s * 32 + 4);
    }

    f32x4 acc[4];
    #pragma unroll
    for (int t = 0; t < 4; ++t) acc[t] = (f32x4){0.f, 0.f, 0.f, 0.f};

    #pragma unroll
    for (int s = 0; s < NSTEP; ++s) {
        // prefetch next step's x frags (L2-hot)
        if (s + 1 < NSTEP) {
            const __bf16* xn = xb + (size_t)(s + 1) * 4 * 64 * 8;
            #pragma unroll
            for (int t = 0; t < 4; ++t)
                xq[(s + 1) & 1][t] = *(const bf16x8*)(xn + (size_t)t * 16 * 8);
        }

        // w frag: scale in f32, then round to bf16 (dequant folded into cvt)
        const float ss = sc[s >> 2];
        const float4 wa = wreg[2 * s], wb = wreg[2 * s + 1];
        bf16x8 wf = {(__bf16)(wa.x * ss), (__bf16)(wa.y * ss),
                     (__bf16)(wa.z * ss), (__bf16)(wa.w * ss),
                     (__bf16)(wb.x * ss), (__bf16)(wb.y * ss),
                     (__bf16)(wb.z * ss), (__bf16)(wb.w * ss)};

        #pragma unroll
        for (int t = 0; t < 4; ++t)
            acc[t] = __builtin_amdgcn_mfma_f32_16x16x32_bf16(xq[s & 1][t], wf,
                                                             acc[t], 0, 0, 0);
    }

    // partials -> ws[ky][m][n]  (C/D: m = t*16 + quad*4 + r, col = ln)
    float* op = ws + ((size_t)ky * Md) * Nd + n0 + wv * 16 + ln;
    #pragma unroll
    for (int t = 0; t < 4; ++t)
        #pragma unroll
        for (int r = 0; r < 4; ++r)
            op[(size_t)(t * 16 + quad * 4 + r) * Nd] = acc[t][r];
}

__global__ __launch_bounds__(256)
void qlinear_reduce(const float* __restrict__ ws,
                    const float* __restrict__ bias,
                    float* __restrict__ out)
{
    const int idx4 = blockIdx.x * 256 + threadIdx.x;   // float4 index
    if (idx4 >= Md * Nd / 4) return;
    const int n4 = idx4 % (Nd / 4);
    float4 v = *(const float4*)(bias + n4 * 4);
    #pragma unroll
    for (int ky = 0; ky < KSPLIT; ++ky) {
        float4 p = *(const float4*)(ws + (size_t)ky * Md * Nd + (size_t)idx4 * 4);
        v.x += p.x; v.y += p.y; v.z += p.z; v.w += p.w;
    }
    *(float4*)(out + (size_t)idx4 * 4) = v;
}

extern "C" void kernel_launch(void* const* d_in, const int* in_sizes, int n_in,
                              void* d_out, int out_size, void* d_ws, size_t ws_size,
                              hipStream_t stream) {
    const float* x     = (const float*)d_in[0];  // [64][4096]
    const float* w     = (const float*)d_in[1];  // [11008][4096]
    const float* scale = (const float*)d_in[2];  // [11008][32]
    const float* bias  = (const float*)d_in[3];  // [11008]
    float* out = (float*)d_out;                  // [64][11008] f32

    float*  ws_part = (float*)d_ws;                          // 45 MB partials
    __bf16* xbf     = (__bf16*)((char*)d_ws + WS_PART_BYTES); // 512 KB bf16 x

    xcvt_kernel<<<128, 256, 0, stream>>>(x, xbf);

    dim3 grid1(Nd / BN, KSPLIT);
    qlinear_pass1<<<grid1, 256, 0, stream>>>(xbf, w, scale, ws_part);

    const int total4 = Md * Nd / 4;              // 176128 = 688 * 256
    qlinear_reduce<<<(total4 + 255) / 256, 256, 0, stream>>>(ws_part, bias, out);
}

// Round 6
// 279.495 us; speedup vs baseline: 1.0297x; 1.0297x over previous
//
#include <hip/hip_runtime.h>

// QuantLinearFP8: out[m,n] = sum_k x[m,k] * w[n,k] * scale[n, k/128] + bias[n]
// M=64, K=4096, N=11008, G=128.
//
// R6: R5 structure with (a) register budget fixed (depth-3 w / depth-2 x
// prefetch, ~112 VGPR < 128 cap -> no spills), (b) ws partials stored in a
// wave-contiguous permuted layout (each store = 1KB contiguous dwordx4/wave,
// no partial-line RMW; reduce un-permutes via index math), (c) KSPLIT=8.
//  - xcvt: x f32 -> bf16 once, A-frag-major [k/8][64][8] (512 KB in ws).
//  - pass1: no LDS, no barriers; w streamed global->reg in B-frag layout,
//    scale folded into the f32->bf16 w cvt (absmax unchanged at 0.0625).
//  - reduce: sum 8 permuted partials + bias -> out (deterministic).

#define Md 64
#define Kd 4096
#define Nd 11008
#define NGROUPS 32
#define BN 64
#define KSPLIT 8
#define KCHUNK 512                 // Kd / KSPLIT
#define NSTEP 16                   // KCHUNK / 32
#define NGRP 4                     // KCHUNK / 128
#define WS_PART_BYTES ((size_t)KSPLIT * Md * Nd * 4)   // 22,544,384 (4096-mult)

typedef __attribute__((ext_vector_type(8))) __bf16 bf16x8;
typedef __attribute__((ext_vector_type(4))) float f32x4;

// ---- pre-pass: x -> bf16, A-frag-major [kgg][m][8], kgg = k/8 ----
__global__ __launch_bounds__(256)
void xcvt_kernel(const float* __restrict__ x, __bf16* __restrict__ xbf)
{
    const int tid = blockIdx.x * 256 + threadIdx.x;   // 32768 = 64 * 512
    const int m   = tid >> 9;       // 0..63
    const int kgg = tid & 511;      // 0..511
    const float* xp = x + (size_t)m * Kd + kgg * 8;
    float4 a = *(const float4*)xp;
    float4 b = *(const float4*)(xp + 4);
    bf16x8 v = {(__bf16)a.x, (__bf16)a.y, (__bf16)a.z, (__bf16)a.w,
                (__bf16)b.x, (__bf16)b.y, (__bf16)b.z, (__bf16)b.w};
    *(bf16x8*)(xbf + ((size_t)kgg * 64 + m) * 8) = v;
}

__global__ __launch_bounds__(256, 4)
void qlinear_pass1(const __bf16* __restrict__ xbf,
                   const float* __restrict__ w,
                   const float* __restrict__ scale,
                   float* __restrict__ ws)
{
    const int tid  = threadIdx.x;
    const int wv   = tid >> 6;
    const int lane = tid & 63;
    const int quad = lane >> 4;
    const int ln   = lane & 15;

    const int n0 = blockIdx.x * BN;
    const int ky = blockIdx.y;

    const int nrow = n0 + wv * 16 + ln;
    const float* wp = w + (size_t)nrow * Kd + ky * KCHUNK + quad * 8;

    // 4 group scales for this chunk (contiguous 16 B)
    float4 sc4 = *(const float4*)(scale + (size_t)nrow * NGROUPS + ky * NGRP);
    const float sc[4] = {sc4.x, sc4.y, sc4.z, sc4.w};

    // x frag base: element j of frag(s,t) = xbf[((ky*64 + s*4 + quad)*64
    //                                            + t*16 + ln)*8 + j]
    const __bf16* xb = xbf + (((size_t)ky * 64 + quad) * 64 + ln) * 8;

    // depth-2 x prefetch (3 rotating slots), depth-3 w prefetch (4 slots)
    bf16x8 xq[3][4];
    float4 wb[4][2];
    #pragma unroll
    for (int s = 0; s < 2; ++s)
        #pragma unroll
        for (int t = 0; t < 4; ++t)
            xq[s][t] = *(const bf16x8*)(xb + (size_t)(s * 256 + t * 16) * 8);
    #pragma unroll
    for (int s = 0; s < 3; ++s) {
        wb[s][0] = *(const float4*)(wp + s * 32);
        wb[s][1] = *(const float4*)(wp + s * 32 + 4);
    }

    f32x4 acc[4];
    #pragma unroll
    for (int t = 0; t < 4; ++t) acc[t] = (f32x4){0.f, 0.f, 0.f, 0.f};

    #pragma unroll
    for (int s = 0; s < NSTEP; ++s) {
        // prefetch w (3 steps ahead) and x (2 steps ahead)
        if (s + 3 < NSTEP) {
            wb[(s + 3) & 3][0] = *(const float4*)(wp + (s + 3) * 32);
            wb[(s + 3) & 3][1] = *(const float4*)(wp + (s + 3) * 32 + 4);
        }
        if (s + 2 < NSTEP) {
            const __bf16* xn = xb + (size_t)((s + 2) * 256) * 8;
            #pragma unroll
            for (int t = 0; t < 4; ++t)
                xq[(s + 2) % 3][t] = *(const bf16x8*)(xn + (size_t)(t * 16) * 8);
        }

        // w frag: dequant folded into f32->bf16 cvt
        const float ss = sc[s >> 2];
        const float4 wa = wb[s & 3][0], wc = wb[s & 3][1];
        bf16x8 wf = {(__bf16)(wa.x * ss), (__bf16)(wa.y * ss),
                     (__bf16)(wa.z * ss), (__bf16)(wa.w * ss),
                     (__bf16)(wc.x * ss), (__bf16)(wc.y * ss),
                     (__bf16)(wc.z * ss), (__bf16)(wc.w * ss)};

        #pragma unroll
        for (int t = 0; t < 4; ++t)
            acc[t] = __builtin_amdgcn_mfma_f32_16x16x32_bf16(xq[s % 3][t], wf,
                                                             acc[t], 0, 0, 0);
    }

    // ws permuted layout: float index =
    //   ky*Md*Nd + (nb*4 + wv)*1024 + t*256 + lane*4 + r
    // -> each dwordx4 store is 1 KB contiguous per wave (no partial lines).
    float* op = ws + (size_t)ky * (Md * Nd)
              + ((size_t)blockIdx.x * 4 + wv) * 1024 + lane * 4;
    #pragma unroll
    for (int t = 0; t < 4; ++t)
        *(f32x4*)(op + t * 256) = acc[t];
}

__global__ __launch_bounds__(256)
void qlinear_reduce(const float* __restrict__ ws,
                    const float* __restrict__ bias,
                    float* __restrict__ out)
{
    const int idx4 = blockIdx.x * 256 + threadIdx.x;   // 176128 total
    if (idx4 >= Md * Nd / 4) return;

    // invert the permutation: idx4 = bw*256 + t*64 + lane
    const int lane = idx4 & 63;
    const int t    = (idx4 >> 6) & 3;
    const int bw   = idx4 >> 8;            // nb*4 + wv
    const int quad = lane >> 4;
    const int ln   = lane & 15;
    const int n    = (bw >> 2) * 64 + (bw & 3) * 16 + ln;
    const int m0   = t * 16 + quad * 4;    // rows m0 + r

    float4 v = {0.f, 0.f, 0.f, 0.f};
    #pragma unroll
    for (int ky = 0; ky < KSPLIT; ++ky) {
        float4 p = *(const float4*)(ws + (size_t)ky * (Md * Nd)
                                    + (size_t)idx4 * 4);
        v.x += p.x; v.y += p.y; v.z += p.z; v.w += p.w;
    }
    const float b = bias[n];
    out[(size_t)(m0 + 0) * Nd + n] = v.x + b;
    out[(size_t)(m0 + 1) * Nd + n] = v.y + b;
    out[(size_t)(m0 + 2) * Nd + n] = v.z + b;
    out[(size_t)(m0 + 3) * Nd + n] = v.w + b;
}

extern "C" void kernel_launch(void* const* d_in, const int* in_sizes, int n_in,
                              void* d_out, int out_size, void* d_ws, size_t ws_size,
                              hipStream_t stream) {
    const float* x     = (const float*)d_in[0];  // [64][4096]
    const float* w     = (const float*)d_in[1];  // [11008][4096]
    const float* scale = (const float*)d_in[2];  // [11008][32]
    const float* bias  = (const float*)d_in[3];  // [11008]
    float* out = (float*)d_out;                  // [64][11008] f32

    float*  ws_part = (float*)d_ws;                           // 22.5 MB
    __bf16* xbf     = (__bf16*)((char*)d_ws + WS_PART_BYTES); // 512 KB

    xcvt_kernel<<<128, 256, 0, stream>>>(x, xbf);

    dim3 grid1(Nd / BN, KSPLIT);
    qlinear_pass1<<<grid1, 256, 0, stream>>>(xbf, w, scale, ws_part);

    const int total4 = Md * Nd / 4;              // 176128 = 688 * 256
    qlinear_reduce<<<(total4 + 255) / 256, 256, 0, stream>>>(ws_part, bias, out);
}